// Round 6
// baseline (19.315 us; speedup 1.0000x reference)
//
#include <hip/hip_runtime.h>

#define DD 256        // feature dim
#define CC 4096       // number of centers
#define NB 128        // blocks (one barrier group; 128 CUs active)
#define TPB 512       // threads/block = 8 waves
#define RPB (CC / NB) // 32 rows per block (4 per wave)
#define D4 (DD / 4)   // 64 float4 columns per row
#define MAGIC 0x05F3A9C1  // != 0 (self-reset) and != 0xAAAAAAAA (ws poison)

// Per-block comm slots padded to one 64 B cacheline each: a publication is a
// single exclusive-line write; a gather is one line fetch. No false sharing
// across XCDs.
struct alignas(64) Comm1 { int flag; float S; int pad[14]; };
struct alignas(64) Comm2 { double cd; double cd2; int flag; int pad[11]; };

// ---------------------------------------------------------------------------
// DensityLoss forward, collapsed O(C^2 D) -> O(C D), ONE graph node:
//   t[d]  = sum_i centers[i][d];  S = sum_i ||c_i||^2
//   cd[i] = (C*||c_i||^2 + S - 2*c_i.t) / (C-1)      (diagonal term == 0)
//   out   = (sum cd / C) / var(cd, ddof=1) / N
// Magic-value flag protocol (proven R3-R5): block b release-stores
// flag=MAGIC after publishing; consumers acquire-spin; block 0 resets all
// flags to 0 at the end (safe: reset happens only after every block has set
// flag2, i.e. passed every spin). Rows live in registers across the barrier;
// centers is read exactly once. All reductions fixed-order -> deterministic.
// ---------------------------------------------------------------------------
__global__ __launch_bounds__(TPB) void fused_density(
    const float* __restrict__ centers,
    float* __restrict__ t_part,  // [NB][DD]
    Comm1* __restrict__ c1,      // [NB]
    Comm2* __restrict__ c2,      // [NB]
    float* __restrict__ out, long long N) {
  const int tx = threadIdx.x, w = tx >> 6, lane = tx & 63, b = blockIdx.x;

  __shared__ float4 smT[8][64];  // wave column partials (8 KB)
  __shared__ float sm2[2][DD];   // half-reduced t partials
  __shared__ float smt[DD];      // final t
  __shared__ float sS[8];
  __shared__ float sSfin;
  __shared__ double sC[8], sC2[8];
  __shared__ double rc[NB], rc2[NB];

  // ---- phase 1: per-block column sums + sum-of-squares (rows -> regs) ----
  const float4* src =
      (const float4*)centers + (size_t)(b * RPB + w * 4) * D4 + lane;
  float4 v0 = src[0 * D4], v1 = src[1 * D4], v2 = src[2 * D4], v3 = src[3 * D4];

  float4 ta;
  ta.x = (v0.x + v1.x) + (v2.x + v3.x);
  ta.y = (v0.y + v1.y) + (v2.y + v3.y);
  ta.z = (v0.z + v1.z) + (v2.z + v3.z);
  ta.w = (v0.w + v1.w) + (v2.w + v3.w);
  smT[w][lane] = ta;
  float ss = (v0.x * v0.x + v0.y * v0.y + v0.z * v0.z + v0.w * v0.w) +
             (v1.x * v1.x + v1.y * v1.y + v1.z * v1.z + v1.w * v1.w) +
             (v2.x * v2.x + v2.y * v2.y + v2.z * v2.z + v2.w * v2.w) +
             (v3.x * v3.x + v3.y * v3.y + v3.z * v3.z + v3.w * v3.w);
  #pragma unroll
  for (int off = 32; off; off >>= 1) ss += __shfl_xor(ss, off, 64);
  if (lane == 0) sS[w] = ss;
  __syncthreads();
  if (tx < 64) {
    float4 s = smT[0][tx];
    #pragma unroll
    for (int k = 1; k < 8; ++k) {
      float4 o = smT[k][tx];
      s.x += o.x; s.y += o.y; s.z += o.z; s.w += o.w;
    }
    ((float4*)t_part)[b * 64 + tx] = s;
  }
  if (tx == 0) {
    float s = 0.f;
    #pragma unroll
    for (int k = 0; k < 8; ++k) s += sS[k];
    c1[b].S = s;
  }
  __syncthreads();  // all of this block's global stores drained (vmcnt 0)
  if (tx == 0)
    __hip_atomic_store(&c1[b].flag, MAGIC, __ATOMIC_RELEASE,
                       __HIP_MEMORY_SCOPE_AGENT);

  // ---- grid barrier: wait for all NB flag1 (one private line per flag) ----
  if (tx < NB) {
    while (__hip_atomic_load(&c1[tx].flag, __ATOMIC_ACQUIRE,
                             __HIP_MEMORY_SCOPE_AGENT) != MAGIC)
      __builtin_amdgcn_s_sleep(1);
  }
  __syncthreads();

  // ---- phase 2: redundant t finalize (512 thr, 8-way ILP over 64 each) ----
  {
    const int col = tx & 255, half = tx >> 8;
    const float* tp = t_part + (size_t)(half * 64) * DD + col;
    float a0 = 0.f, a1 = 0.f, a2 = 0.f, a3 = 0.f;
    float a4 = 0.f, a5 = 0.f, a6 = 0.f, a7 = 0.f;
    #pragma unroll
    for (int p = 0; p < 64; p += 8) {
      a0 += tp[(p + 0) * DD]; a1 += tp[(p + 1) * DD];
      a2 += tp[(p + 2) * DD]; a3 += tp[(p + 3) * DD];
      a4 += tp[(p + 4) * DD]; a5 += tp[(p + 5) * DD];
      a6 += tp[(p + 6) * DD]; a7 += tp[(p + 7) * DD];
    }
    sm2[half][col] = ((a0 + a1) + (a2 + a3)) + ((a4 + a5) + (a6 + a7));
  }
  __syncthreads();
  if (tx < DD) smt[tx] = sm2[0][tx] + sm2[1][tx];
  if (tx >= 256 && tx < 320) {  // wave 4: S = butterfly over 128 slots
    const int l = tx - 256;
    float sv = c1[l].S + c1[l + 64].S;
    #pragma unroll
    for (int off = 32; off; off >>= 1) sv += __shfl_xor(sv, off, 64);
    if (l == 0) sSfin = sv;
  }
  __syncthreads();
  const float S = sSfin;
  const float4 t4 = ((const float4*)smt)[lane];

  // ---- phase 3: cd for this block's rows (still in registers) ----
  const float Cf = (float)CC;
  const double inv = 1.0 / (double)(CC - 1);
  double cds = 0.0, cd2 = 0.0;
  #pragma unroll
  for (int r = 0; r < 4; ++r) {
    float4 v = (r == 0) ? v0 : (r == 1) ? v1 : (r == 2) ? v2 : v3;
    float u = (Cf * v.x - 2.f * t4.x) * v.x + (Cf * v.y - 2.f * t4.y) * v.y +
              (Cf * v.z - 2.f * t4.z) * v.z + (Cf * v.w - 2.f * t4.w) * v.w;
    #pragma unroll
    for (int off = 32; off; off >>= 1) u += __shfl_xor(u, off, 64);
    if (lane == 0) {
      double cd = ((double)u + (double)S) * inv;
      cds += cd;
      cd2 += cd * cd;
    }
  }
  if (lane == 0) { sC[w] = cds; sC2[w] = cd2; }
  __syncthreads();
  if (tx == 0) {
    double bc = 0.0, bc2 = 0.0;
    #pragma unroll
    for (int k = 0; k < 8; ++k) { bc += sC[k]; bc2 += sC2[k]; }
    c2[b].cd = bc;
    c2[b].cd2 = bc2;
    __hip_atomic_store(&c2[b].flag, MAGIC, __ATOMIC_RELEASE,
                       __HIP_MEMORY_SCOPE_AGENT);  // same line: one-line publish
  }

  // ---- phase 4: block 0 gathers, combines (fixed order), resets flags ----
  if (b == 0) {
    if (tx < NB) {
      while (__hip_atomic_load(&c2[tx].flag, __ATOMIC_ACQUIRE,
                               __HIP_MEMORY_SCOPE_AGENT) != MAGIC)
        __builtin_amdgcn_s_sleep(1);
      rc[tx] = c2[tx].cd;
      rc2[tx] = c2[tx].cd2;
    }
    __syncthreads();
    #pragma unroll
    for (int st = 64; st; st >>= 1) {
      if (tx < st) { rc[tx] += rc[tx + st]; rc2[tx] += rc2[tx + st]; }
      __syncthreads();
    }
    if (tx == 0) {
      double s = rc[0], s2 = rc2[0];
      double mean = s / (double)CC;
      double var = (s2 - s * s / (double)CC) / (double)(CC - 1);
      out[0] = (float)(mean / var / (double)N);
    }
    // every block has set flag2 => every block passed every spin => safe
    if (tx < NB) {
      __hip_atomic_store(&c1[tx].flag, 0, __ATOMIC_RELEASE,
                         __HIP_MEMORY_SCOPE_AGENT);
      __hip_atomic_store(&c2[tx].flag, 0, __ATOMIC_RELEASE,
                         __HIP_MEMORY_SCOPE_AGENT);
    }
  }
}

extern "C" void kernel_launch(void* const* d_in, const int* in_sizes, int n_in,
                              void* d_out, int out_size, void* d_ws,
                              size_t ws_size, hipStream_t stream) {
  const float* centers = (const float*)d_in[0];
  long long N = (long long)in_sizes[2];  // labels.shape[0]
  (void)n_in; (void)out_size; (void)ws_size;

  // ws layout: t_part 128 KB | Comm1[128] 8 KB | Comm2[128] 8 KB
  char* ws = (char*)d_ws;
  float* t_part = (float*)ws;                  // 131072 B
  Comm1* c1 = (Comm1*)(ws + 131072);           // 8192 B
  Comm2* c2 = (Comm2*)(ws + 131072 + 8192);    // 8192 B
  float* outp = (float*)d_out;

  hipLaunchKernelGGL(fused_density, dim3(NB), dim3(TPB), 0, stream, centers,
                     t_part, c1, c2, outp, N);
}

// Round 7
// 17.845 us; speedup vs baseline: 1.0824x; 1.0824x over previous
//
#include <hip/hip_runtime.h>

#define DD 256        // feature dim
#define CC 4096       // number of centers
#define NB 64         // blocks (one barrier group)
#define TPB 1024      // threads/block = 16 waves
#define RPB (CC / NB) // 64 rows per block (4 per wave)
#define D4 (DD / 4)   // 64 float4 columns per row
#define MAGIC 0x05F3A9C1  // != 0 (self-reset) and != 0xAAAAAAAA (ws poison)

// ---------------------------------------------------------------------------
// DensityLoss forward, collapsed O(C^2 D) -> O(C D), ONE graph node:
//   t[d]  = sum_i centers[i][d];  S = sum_i ||c_i||^2
//   cd[i] = (C*||c_i||^2 + S - 2*c_i.t) / (C-1)      (diagonal term == 0)
//   out   = (sum cd / C) / var(cd, ddof=1) / N
// Proven R5 structure: packed magic-value flag arrays (one line fetch
// observes 16 flags while spinning), block 0 self-resets flags at the end
// (safe: reset happens only after every block has set flag2, i.e. passed
// every spin; poison value 0xAAAAAAAA != MAGIC too). Rows live in registers
// across the barrier; centers is read exactly once. All reductions are
// fixed-order trees/butterflies -> deterministic.
// Only change vs R5: phase-2 t-finalize uses all 1024 threads (4 per column,
// 16 partials each, 8-way ILP -> 2 latency rounds instead of 4).
// ---------------------------------------------------------------------------
__global__ __launch_bounds__(TPB) void fused_density(
    const float* __restrict__ centers,
    float* __restrict__ t_part,    // [NB][DD]
    float* __restrict__ S_part,    // [NB]
    double* __restrict__ cd_part,  // [NB]
    double* __restrict__ cd2_part, // [NB]
    int* __restrict__ flag1,       // [NB] packed
    int* __restrict__ flag2,       // [NB] packed
    float* __restrict__ out, long long N) {
  const int tx = threadIdx.x, w = tx >> 6, lane = tx & 63, b = blockIdx.x;

  __shared__ float4 smT[16][64];  // wave column partials (16 KB)
  __shared__ float sm4[4][DD];    // quarter-reduced t partials (4 KB)
  __shared__ float smt[DD];       // final t
  __shared__ float sSfin;
  __shared__ float sS[16];
  __shared__ double sC[16], sC2[16];
  __shared__ double rc[NB], rc2[NB];

  // ---- phase 1: per-block column sums + sum-of-squares (rows -> regs) ----
  const float4* src =
      (const float4*)centers + (size_t)(b * RPB + w * 4) * D4 + lane;
  float4 v0 = src[0 * D4], v1 = src[1 * D4], v2 = src[2 * D4], v3 = src[3 * D4];

  float4 ta;
  ta.x = (v0.x + v1.x) + (v2.x + v3.x);
  ta.y = (v0.y + v1.y) + (v2.y + v3.y);
  ta.z = (v0.z + v1.z) + (v2.z + v3.z);
  ta.w = (v0.w + v1.w) + (v2.w + v3.w);
  smT[w][lane] = ta;
  float ss = (v0.x * v0.x + v0.y * v0.y + v0.z * v0.z + v0.w * v0.w) +
             (v1.x * v1.x + v1.y * v1.y + v1.z * v1.z + v1.w * v1.w) +
             (v2.x * v2.x + v2.y * v2.y + v2.z * v2.z + v2.w * v2.w) +
             (v3.x * v3.x + v3.y * v3.y + v3.z * v3.z + v3.w * v3.w);
  #pragma unroll
  for (int off = 32; off; off >>= 1) ss += __shfl_xor(ss, off, 64);
  if (lane == 0) sS[w] = ss;
  __syncthreads();
  if (tx < 64) {
    float4 s = smT[0][tx];
    #pragma unroll
    for (int k = 1; k < 16; ++k) {
      float4 o = smT[k][tx];
      s.x += o.x; s.y += o.y; s.z += o.z; s.w += o.w;
    }
    ((float4*)t_part)[b * 64 + tx] = s;
  }
  if (tx == 0) {
    float s = 0.f;
    #pragma unroll
    for (int k = 0; k < 16; ++k) s += sS[k];
    S_part[b] = s;
  }
  __syncthreads();  // block's t_part/S_part stores complete before release
  if (tx == 0)
    __hip_atomic_store(&flag1[b], MAGIC, __ATOMIC_RELEASE,
                       __HIP_MEMORY_SCOPE_AGENT);

  // ---- grid barrier: every block waits for all 64 flag1 (packed spin) ----
  if (tx < NB) {
    while (__hip_atomic_load(&flag1[tx], __ATOMIC_ACQUIRE,
                             __HIP_MEMORY_SCOPE_AGENT) != MAGIC)
      __builtin_amdgcn_s_sleep(1);
  }
  __syncthreads();

  // ---- phase 2: t finalize, all 1024 threads (4/column, 8-way ILP) ----
  {
    const int col = tx & 255, q = tx >> 8;  // q in 0..3, 16 partials each
    const float* tp = t_part + (size_t)(q * 16) * DD + col;
    float a0 = 0.f, a1 = 0.f, a2 = 0.f, a3 = 0.f;
    float a4 = 0.f, a5 = 0.f, a6 = 0.f, a7 = 0.f;
    #pragma unroll
    for (int p = 0; p < 16; p += 8) {
      a0 += tp[(p + 0) * DD]; a1 += tp[(p + 1) * DD];
      a2 += tp[(p + 2) * DD]; a3 += tp[(p + 3) * DD];
      a4 += tp[(p + 4) * DD]; a5 += tp[(p + 5) * DD];
      a6 += tp[(p + 6) * DD]; a7 += tp[(p + 7) * DD];
    }
    sm4[q][col] = ((a0 + a1) + (a2 + a3)) + ((a4 + a5) + (a6 + a7));
  }
  __syncthreads();
  if (tx < DD) {
    smt[tx] = (sm4[0][tx] + sm4[1][tx]) + (sm4[2][tx] + sm4[3][tx]);
  } else if (tx >= 256 && tx < 320) {  // wave 4: S via one 64-lane butterfly
    float sv = S_part[tx - 256];
    #pragma unroll
    for (int off = 32; off; off >>= 1) sv += __shfl_xor(sv, off, 64);
    if (tx == 256) sSfin = sv;
  }
  __syncthreads();
  const float S = sSfin;
  const float4 t4 = ((const float4*)smt)[lane];

  // ---- phase 3: cd for this block's rows (still in registers) ----
  const float Cf = (float)CC;
  const double inv = 1.0 / (double)(CC - 1);
  double cds = 0.0, cd2 = 0.0;
  #pragma unroll
  for (int r = 0; r < 4; ++r) {
    float4 v = (r == 0) ? v0 : (r == 1) ? v1 : (r == 2) ? v2 : v3;
    float u = (Cf * v.x - 2.f * t4.x) * v.x + (Cf * v.y - 2.f * t4.y) * v.y +
              (Cf * v.z - 2.f * t4.z) * v.z + (Cf * v.w - 2.f * t4.w) * v.w;
    #pragma unroll
    for (int off = 32; off; off >>= 1) u += __shfl_xor(u, off, 64);
    if (lane == 0) {
      double cd = ((double)u + (double)S) * inv;
      cds += cd;
      cd2 += cd * cd;
    }
  }
  if (lane == 0) { sC[w] = cds; sC2[w] = cd2; }
  __syncthreads();
  if (tx == 0) {
    double bc = 0.0, bc2 = 0.0;
    #pragma unroll
    for (int k = 0; k < 16; ++k) { bc += sC[k]; bc2 += sC2[k]; }
    __hip_atomic_store(&cd_part[b], bc, __ATOMIC_RELEASE,
                       __HIP_MEMORY_SCOPE_AGENT);
    __hip_atomic_store(&cd2_part[b], bc2, __ATOMIC_RELEASE,
                       __HIP_MEMORY_SCOPE_AGENT);
    __hip_atomic_store(&flag2[b], MAGIC, __ATOMIC_RELEASE,
                       __HIP_MEMORY_SCOPE_AGENT);
  }

  // ---- phase 4: block 0 gathers, combines (fixed order), resets flags ----
  if (b == 0) {
    if (tx < NB) {
      while (__hip_atomic_load(&flag2[tx], __ATOMIC_ACQUIRE,
                               __HIP_MEMORY_SCOPE_AGENT) != MAGIC)
        __builtin_amdgcn_s_sleep(1);
      rc[tx] = cd_part[tx];
      rc2[tx] = cd2_part[tx];
    }
    __syncthreads();
    #pragma unroll
    for (int st = 32; st; st >>= 1) {
      if (tx < st) { rc[tx] += rc[tx + st]; rc2[tx] += rc2[tx + st]; }
      __syncthreads();
    }
    if (tx == 0) {
      double s = rc[0], s2 = rc2[0];
      double mean = s / (double)CC;
      double var = (s2 - s * s / (double)CC) / (double)(CC - 1);
      out[0] = (float)(mean / var / (double)N);
    }
    // every block has set flag2 => every block passed every spin => safe
    if (tx < NB) {
      __hip_atomic_store(&flag1[tx], 0, __ATOMIC_RELEASE,
                         __HIP_MEMORY_SCOPE_AGENT);
      __hip_atomic_store(&flag2[tx], 0, __ATOMIC_RELEASE,
                         __HIP_MEMORY_SCOPE_AGENT);
    }
  }
}

extern "C" void kernel_launch(void* const* d_in, const int* in_sizes, int n_in,
                              void* d_out, int out_size, void* d_ws,
                              size_t ws_size, hipStream_t stream) {
  const float* centers = (const float*)d_in[0];
  long long N = (long long)in_sizes[2];  // labels.shape[0]
  (void)n_in; (void)out_size; (void)ws_size;

  // ws layout: t_part 64KB | S_part 256B | pad | cd 512B | cd2 512B | flags
  char* ws = (char*)d_ws;
  float* t_part = (float*)ws;                    // 65536 B
  float* S_part = (float*)(ws + 65536);          // 256 B
  double* cd_part = (double*)(ws + 66048);       // 512 B (8B aligned)
  double* cd2_part = (double*)(ws + 66560);      // 512 B
  int* flag1 = (int*)(ws + 67072);               // 256 B
  int* flag2 = (int*)(ws + 67328);               // 256 B
  float* outp = (float*)d_out;

  hipLaunchKernelGGL(fused_density, dim3(NB), dim3(TPB), 0, stream, centers,
                     t_part, S_part, cd_part, cd2_part, flag1, flag2, outp, N);
}